// Round 7
// baseline (385.409 us; speedup 1.0000x reference)
//
#include <hip/hip_runtime.h>
#include <math.h>

// Problem constants (match reference)
#define PP 6
#define MM 512
#define NN 4096
#define DD 1024
#define KSCALE 15.0f
#define BIGV 1e9f

// Tiling
#define BM 128
#define BN 128
#define BK 16
#define NCHUNK (DD / BK)    // 64
#define NSTRIP (NN / BN)    // 32
#define KI 6
#define KR 12
#define PARTW 20            // 6 intra + 12 inter + 2 sums
#define LDSB 16384          // bytes per staging buffer
#define NBUF 4              // depth-3 prefetch pipeline

typedef __bf16 bf16x8 __attribute__((ext_vector_type(8)));
typedef float  f32x16 __attribute__((ext_vector_type(16)));

// branchless sorted-insert (ascending, drops largest)
__device__ __forceinline__ void insert6(float (&a)[KI], float v) {
    if (v < a[KI - 1]) {
        float cur = v;
#pragma unroll
        for (int x = 0; x < KI; ++x) {
            float lo = fminf(a[x], cur);
            float hi = fmaxf(a[x], cur);
            a[x] = lo; cur = hi;
        }
    }
}
__device__ __forceinline__ void insert12(float (&a)[KR], float v) {
    if (v < a[KR - 1]) {
        float cur = v;
#pragma unroll
        for (int x = 0; x < KR; ++x) {
            float lo = fminf(a[x], cur);
            float hi = fmaxf(a[x], cur);
            a[x] = lo; cur = hi;
        }
    }
}

// ---------- decompose: fp32 -> hi/lo bf16 planes (+ c2 for centers) ----------
// one wave per 1024-float row; rows [0, P*M) = feature, [P*M, P*M+P*N) = centers

__global__ __launch_bounds__(256)
void decomp_all(const float* __restrict__ feature, const float* __restrict__ centers,
                __bf16* __restrict__ Fhi, __bf16* __restrict__ Flo,
                __bf16* __restrict__ Chi, __bf16* __restrict__ Clo,
                float* __restrict__ c2, float* __restrict__ out) {
    if (blockIdx.x == 0 && threadIdx.x == 0) out[0] = 0.0f;   // un-poison output
    const int r    = blockIdx.x * 4 + (threadIdx.x >> 6);
    const int lane = threadIdx.x & 63;
    const float* src;
    __bf16 *dhi, *dlo;
    int row;
    bool isC;
    if (r < PP * MM) { src = feature; dhi = Fhi; dlo = Flo; row = r; isC = false; }
    else             { src = centers; dhi = Chi; dlo = Clo; row = r - PP * MM; isC = true; }
    const size_t eb = (size_t)row * DD + lane * 16;
    float s = 0.0f;
#pragma unroll
    for (int g = 0; g < 2; ++g) {
        float4 v0 = *(const float4*)(src + eb + g * 8);
        float4 v1 = *(const float4*)(src + eb + g * 8 + 4);
        float fv[8] = {v0.x, v0.y, v0.z, v0.w, v1.x, v1.y, v1.z, v1.w};
        bf16x8 h, l;
#pragma unroll
        for (int i = 0; i < 8; ++i) {
            s = fmaf(fv[i], fv[i], s);
            __bf16 hh = (__bf16)fv[i];
            h[i] = hh;
            l[i] = (__bf16)(fv[i] - (float)hh);
        }
        *(bf16x8*)(dhi + eb + g * 8) = h;
        *(bf16x8*)(dlo + eb + g * 8) = l;
    }
#pragma unroll
    for (int off = 32; off > 0; off >>= 1) s += __shfl_down(s, off, 64);
    if (isC && lane == 0) c2[row] = s;
}

// ---------- fused distance GEMM (split-bf16 MFMA, counted-vmcnt pipeline) ----
// d' = c2[n] - 2*dot  (f2[m] cancels in -x+y and preserves sort order).

__global__ __launch_bounds__(256, 2)
void dist_topk_kernel(const __bf16* __restrict__ Fhi, const __bf16* __restrict__ Flo,
                      const __bf16* __restrict__ Chi, const __bf16* __restrict__ Clo,
                      const float* __restrict__ c2g,
                      const int* __restrict__ camid, const int* __restrict__ cam,
                      float* __restrict__ partials) {
    const int ns = blockIdx.x;          // 0..31 column strip
    const int mt = blockIdx.y;          // 0..3  row tile
    const int p  = blockIdx.z;          // 0..5
    const int t  = threadIdx.x;
    const int lane = t & 63, w = t >> 6;
    const int wr = w >> 1, wc = w & 1;  // 2x2 wave grid, 64x64 per wave
    const int l31 = lane & 31, lh = lane >> 5;

    // staging: 4 buffers x 16KB (depth-3 prefetch), LINEAR layout
    //   unit16B = plane*512 + ks*256 + row ; rows 0..127 = A, 128..255 = B
    // band buffer [128][33] f32 unioned over buffers 0..1 (used after K-loop)
    __shared__ __align__(16) char smem[NBUF * LDSB];
    __shared__ int s_cam[BN];
    float* bandS = (float*)smem;

    // per-thread staging sources: 4 global_load_lds issues per chunk
    const char* srcp[4];
    int ldsoff[4];
#pragma unroll
    for (int i = 0; i < 4; ++i) {
        const int r_idx = w * 4 + i;
        const int plane = r_idx >> 3;
        const int ks    = (r_idx >> 2) & 1;
        const int row   = (r_idx & 3) * 64 + lane;
        const __bf16* basep;
        size_t gr;
        if (row < BM) { basep = plane ? Flo : Fhi; gr = (size_t)(p * MM + mt * BM + row) * DD; }
        else          { basep = plane ? Clo : Chi; gr = (size_t)(p * NN + ns * BN + row - BM) * DD; }
        srcp[i]   = (const char*)(basep + gr + ks * 8);
        ldsoff[i] = r_idx * 1024;       // wave-uniform LDS base; HW adds lane*16
    }

    // fragment read byte offsets (within a buffer)
    int aU[2], bU[2];
#pragma unroll
    for (int x = 0; x < 2; ++x) {
        aU[x] = (lh * 256 + wr * 64 + x * 32 + l31) * 16;
        bU[x] = (lh * 256 + 128 + wc * 64 + x * 32 + l31) * 16;
    }

    f32x16 acc[2][2];
#pragma unroll
    for (int i = 0; i < 2; ++i)
#pragma unroll
        for (int j = 0; j < 2; ++j)
#pragma unroll
            for (int r = 0; r < 16; ++r) acc[i][j][r] = 0.0f;

    auto stage = [&](int buf, int c) {
#pragma unroll
        for (int i = 0; i < 4; ++i)
            __builtin_amdgcn_global_load_lds(
                (const __attribute__((address_space(1))) void*)(srcp[i] + (size_t)c * 32),
                (__attribute__((address_space(3))) void*)(smem + buf * LDSB + ldsoff[i]),
                16, 0, 0);
    };

    // prologue: depth-3 prefetch
    stage(0, 0); stage(1, 1); stage(2, 2);

    for (int c = 0; c < NCHUNK; ++c) {
        // wait for chunk c's stage only (4 loads); keep deeper prefetch in flight
        if (c + 2 < NCHUNK)      asm volatile("s_waitcnt vmcnt(8)" ::: "memory");
        else if (c + 1 < NCHUNK) asm volatile("s_waitcnt vmcnt(4)" ::: "memory");
        else                     asm volatile("s_waitcnt vmcnt(0)" ::: "memory");
        __builtin_amdgcn_s_barrier();
        if (c + 3 < NCHUNK) stage((c + 3) & 3, c + 3);

        const char* bb = smem + (c & 3) * LDSB;
        bf16x8 ah[2], al[2], bh[2], bl[2];
#pragma unroll
        for (int x = 0; x < 2; ++x) {
            ah[x] = *(const bf16x8*)(bb + aU[x]);
            al[x] = *(const bf16x8*)(bb + 8192 + aU[x]);
            bh[x] = *(const bf16x8*)(bb + bU[x]);
            bl[x] = *(const bf16x8*)(bb + 8192 + bU[x]);
        }
        asm volatile("s_waitcnt lgkmcnt(0)" ::: "memory");
        __builtin_amdgcn_sched_barrier(0);
        __builtin_amdgcn_s_setprio(1);
#pragma unroll
        for (int mi = 0; mi < 2; ++mi)
#pragma unroll
            for (int nj = 0; nj < 2; ++nj) {
                acc[mi][nj] = __builtin_amdgcn_mfma_f32_32x32x16_bf16(
                    ah[mi], bh[nj], acc[mi][nj], 0, 0, 0);
                acc[mi][nj] = __builtin_amdgcn_mfma_f32_32x32x16_bf16(
                    ah[mi], bl[nj], acc[mi][nj], 0, 0, 0);
                acc[mi][nj] = __builtin_amdgcn_mfma_f32_32x32x16_bf16(
                    al[mi], bh[nj], acc[mi][nj], 0, 0, 0);
            }
        __builtin_amdgcn_s_setprio(0);
    }

    __syncthreads();                    // full drain; staging LDS now reusable

    // epilogue-only global loads (kept out of the K-loop's vmcnt accounting)
    if (t < BN) s_cam[t] = cam[ns * BN + t];
    float c2v[2];
#pragma unroll
    for (int nj = 0; nj < 2; ++nj)
        c2v[nj] = c2g[p * NN + ns * BN + wc * 64 + nj * 32 + l31];

    const int myrow = t >> 1, half = t & 1;   // 2 threads per row
    const int my_cam = camid[mt * BM + myrow];
    float ti[KI], tr[KR];
#pragma unroll
    for (int x = 0; x < KI; ++x) ti[x] = BIGV;
#pragma unroll
    for (int x = 0; x < KR; ++x) tr[x] = BIGV;
    float si = 0.0f, sr = 0.0f;

    // 4 column-bands of 32 cols; band b written by waves with wc == b>>1 (nj = b&1)
#pragma unroll
    for (int b = 0; b < 4; ++b) {
        __syncthreads();                 // previous band consumed; s_cam visible
        if (wc == (b >> 1)) {
            const int nj = b & 1;
#pragma unroll
            for (int mi = 0; mi < 2; ++mi)
#pragma unroll
                for (int r = 0; r < 16; ++r) {
                    // C/D layout: col = lane&31, row = (r&3)+8*(r>>2)+4*(lane>>5)
                    int R = wr * 64 + mi * 32 + (r & 3) + 8 * (r >> 2) + 4 * lh;
                    bandS[R * 33 + l31] = c2v[nj] - 2.0f * acc[mi][nj][r];
                }
        }
        __syncthreads();
        const float* drow = bandS + myrow * 33 + half * 16;
        const int*   crow = s_cam + b * 32 + half * 16;
#pragma unroll
        for (int j = 0; j < 16; ++j) {
            float dd = drow[j];
            float e  = __expf(-KSCALE * dd);
            if (crow[j] == my_cam) { si += e; insert6(ti, dd); }
            else                   { sr += e; insert12(tr, dd); }
        }
    }

    // merge the 2 threads per row via lane^1 shuffle (snapshot first, then insert)
    float oti[KI], otr[KR];
#pragma unroll
    for (int x = 0; x < KI; ++x) oti[x] = __shfl_xor(ti[x], 1, 64);
#pragma unroll
    for (int x = 0; x < KR; ++x) otr[x] = __shfl_xor(tr[x], 1, 64);
    float osi = __shfl_xor(si, 1, 64), osr = __shfl_xor(sr, 1, 64);
#pragma unroll
    for (int x = 0; x < KI; ++x) insert6(ti, oti[x]);
#pragma unroll
    for (int x = 0; x < KR; ++x) insert12(tr, otr[x]);
    si += osi; sr += osr;

    if (!half) {
        float* outp = partials +
            ((size_t)(p * MM + mt * BM + myrow) * NSTRIP + ns) * PARTW;
#pragma unroll
        for (int x = 0; x < KI; ++x) outp[x] = ti[x];
#pragma unroll
        for (int x = 0; x < KR; ++x) outp[KI + x] = tr[x];
        outp[18] = si; outp[19] = sr;
    }
}

// ---------- finalize: one wave per row, lane=strip, shuffle-butterfly merge ----

__global__ __launch_bounds__(256)
void finalize_kernel(const float* __restrict__ partials, float* __restrict__ out) {
    const int t = threadIdx.x, lane = t & 63, w = t >> 6;
    const int row = blockIdx.x * 4 + w;        // 0..P*M-1
    const int strip = lane & 31;               // lanes 32-63 mirror (harmless)
    const float* q = partials + ((size_t)row * NSTRIP + strip) * PARTW;
    float ti[KI], tr[KR];
#pragma unroll
    for (int x = 0; x < KI; ++x) ti[x] = q[x];
#pragma unroll
    for (int x = 0; x < KR; ++x) tr[x] = q[KI + x];
    float si = q[18], sr = q[19];

#pragma unroll
    for (int s = 1; s < 32; s <<= 1) {
        float oti[KI], otr[KR];
#pragma unroll
        for (int x = 0; x < KI; ++x) oti[x] = __shfl_xor(ti[x], s, 64);
#pragma unroll
        for (int x = 0; x < KR; ++x) otr[x] = __shfl_xor(tr[x], s, 64);
        float osi = __shfl_xor(si, s, 64), osr = __shfl_xor(sr, s, 64);
#pragma unroll
        for (int x = 0; x < KI; ++x) insert6(ti, oti[x]);
#pragma unroll
        for (int x = 0; x < KR; ++x) insert12(tr, otr[x]);
        si += osi; sr += osr;
    }

    if (lane == 0) {
        float ei[KI], er[KR];
#pragma unroll
        for (int x = 0; x < KI; ++x) ei[x] = __expf(-KSCALE * ti[x]);
#pragma unroll
        for (int x = 0; x < KR; ++x) er[x] = __expf(-KSCALE * tr[x]);
        float x_intra = logf(ei[0] + ei[1] + ei[2] + ei[3]);
        float top6 = ei[0] + ei[1] + ei[2] + ei[3] + ei[4] + ei[5];
        float y_intra = logf(fmaxf(si - top6, 0.0f));   // exp(-15*BIG)=0 matches ref
        float x_inter = logf(er[0] + er[1] + er[2] + er[3] +
                             er[4] + er[5] + er[6] + er[7]);
        float top12 = 0.0f;
#pragma unroll
        for (int x = 0; x < KR; ++x) top12 += er[x];
        float y_inter = logf(fmaxf(sr - top12, 0.0f));
        float h = fmaxf(y_intra - x_intra + 12.0f, 0.0f) +
                  fmaxf(y_inter - x_inter + 5.0f, 0.0f);
        atomicAdd(out, h * (1.0f / (MM * PP)));
    }
}

extern "C" void kernel_launch(void* const* d_in, const int* in_sizes, int n_in,
                              void* d_out, int out_size, void* d_ws, size_t ws_size,
                              hipStream_t stream) {
    const float* feature = (const float*)d_in[0];   // [P,M,D] fp32
    const int*   camid   = (const int*)  d_in[1];   // [M]
    const float* centers = (const float*)d_in[2];   // [P,N,D] fp32
    const int*   cam     = (const int*)  d_in[3];   // [N]
    float* out = (float*)d_out;

    // ws layout (bytes):
    //   Chi 50,331,648 | Clo 50,331,648 | Fhi 6,291,456 | Flo 6,291,456
    //   c2 98,304 | partials 7,864,320   -> total 121,208,832
    char* ws = (char*)d_ws;
    __bf16* Chi = (__bf16*)(ws);
    __bf16* Clo = (__bf16*)(ws + 50331648);
    __bf16* Fhi = (__bf16*)(ws + 100663296);
    __bf16* Flo = (__bf16*)(ws + 106954752);
    float*  c2  = (float*) (ws + 113246208);
    float*  partials = (float*)(ws + 113344512);

    decomp_all<<<(PP * (MM + NN)) / 4, 256, 0, stream>>>(feature, centers,
                                                         Fhi, Flo, Chi, Clo,
                                                         c2, out);
    dim3 grid(NSTRIP, MM / BM, PP);
    dist_topk_kernel<<<grid, 256, 0, stream>>>(Fhi, Flo, Chi, Clo, c2,
                                               camid, cam, partials);
    finalize_kernel<<<(PP * MM) / 4, 256, 0, stream>>>(partials, out);
}

// Round 10
// 337.111 us; speedup vs baseline: 1.1433x; 1.1433x over previous
//
#include <hip/hip_runtime.h>
#include <math.h>

// Problem constants (match reference)
#define PP 6
#define MM 512
#define NN 4096
#define DD 1024
#define KSCALE 15.0f
#define BIGV 1e9f

// Tiling
#define BM 128
#define BN 128
#define BK 16
#define NCHUNK (DD / BK)    // 64
#define NSTRIP (NN / BN)    // 32
#define KI 6
#define KR 12
#define PARTW 20            // 6 intra + 12 inter + 2 sums
#define LDSB 16384          // bytes per staging buffer: A-hi|A-lo|B-hi|B-lo 4KB each
#define NBUF 3              // ring, depth-2 prefetch -> 48KB -> 3 blocks/CU

typedef __bf16 bf16x8 __attribute__((ext_vector_type(8)));
typedef float  f32x16 __attribute__((ext_vector_type(16)));

// branchless sorted-insert (ascending, drops largest)
__device__ __forceinline__ void insert6(float (&a)[KI], float v) {
    if (v < a[KI - 1]) {
        float cur = v;
#pragma unroll
        for (int x = 0; x < KI; ++x) {
            float lo = fminf(a[x], cur);
            float hi = fmaxf(a[x], cur);
            a[x] = lo; cur = hi;
        }
    }
}
__device__ __forceinline__ void insert12(float (&a)[KR], float v) {
    if (v < a[KR - 1]) {
        float cur = v;
#pragma unroll
        for (int x = 0; x < KR; ++x) {
            float lo = fminf(a[x], cur);
            float hi = fmaxf(a[x], cur);
            a[x] = lo; cur = hi;
        }
    }
}

// 8 fp32 -> hi/lo bf16x8 (split precision: x = hi + lo + O(2^-17 x))
__device__ __forceinline__ void cvt8(const float4& v0, const float4& v1,
                                     bf16x8& hi, bf16x8& lo) {
    float f[8] = {v0.x, v0.y, v0.z, v0.w, v1.x, v1.y, v1.z, v1.w};
#pragma unroll
    for (int i = 0; i < 8; ++i) {
        __bf16 h = (__bf16)f[i];
        hi[i] = h;
        lo[i] = (__bf16)(f[i] - (float)h);
    }
}

__device__ __forceinline__ float sq8(const float4& a, const float4& b) {
    float s = a.x * a.x;
    s = fmaf(a.y, a.y, s); s = fmaf(a.z, a.z, s); s = fmaf(a.w, a.w, s);
    s = fmaf(b.x, b.x, s); s = fmaf(b.y, b.y, s);
    s = fmaf(b.z, b.z, s); s = fmaf(b.w, b.w, s);
    return s;
}

// ---------- decompose FEATURE only: fp32 -> hi/lo bf16 planes (12.6 MB) ------
// one wave per 1024-float row; fully coalesced (lane*8 within 512-elem group)

__global__ __launch_bounds__(256)
void decomp_feat(const float* __restrict__ f,
                 __bf16* __restrict__ Fhi, __bf16* __restrict__ Flo,
                 float* __restrict__ out) {
    if (blockIdx.x == 0 && threadIdx.x == 0) out[0] = 0.0f;   // un-poison output
    const int row  = blockIdx.x * 4 + (threadIdx.x >> 6);
    const int lane = threadIdx.x & 63;
#pragma unroll
    for (int g = 0; g < 2; ++g) {
        const size_t eb = (size_t)row * DD + g * 512 + lane * 8;
        float4 v0 = *(const float4*)(f + eb);
        float4 v1 = *(const float4*)(f + eb + 4);
        bf16x8 h, l;
        cvt8(v0, v1, h, l);
        *(bf16x8*)(Fhi + eb) = h;
        *(bf16x8*)(Flo + eb) = l;
    }
}

// ---------- fused distance GEMM: A from bf16 planes via global_load_lds, ----
// ---------- B (centers) converted in-kernel (fp32 -> hi/lo), c2 on the fly --
// d' = c2[n] - 2*dot  (f2[m] cancels in -x+y and preserves sort order).

__global__ __launch_bounds__(256, 3)
void dist_topk_kernel(const __bf16* __restrict__ Fhi, const __bf16* __restrict__ Flo,
                      const float* __restrict__ centers,
                      const int* __restrict__ camid, const int* __restrict__ cam,
                      float* __restrict__ partials) {
    const int ns = blockIdx.x;          // 0..31 column strip
    const int mt = blockIdx.y;          // 0..3  row tile
    const int p  = blockIdx.z;          // 0..5
    const int t  = threadIdx.x;
    const int lane = t & 63, w = t >> 6;
    const int wr = w >> 1, wc = w & 1;  // 2x2 wave grid, 64x64 per wave
    const int l31 = lane & 31, lh = lane >> 5;

    // 3 x 16KB ring buffers. Per buffer (byte offsets):
    //   A-hi [ks][128row] @0      A-lo @4096   (staged via global_load_lds)
    //   B-hi [ks][128row] @8192   B-lo @12288  (reg-staged + cvt + ds_write)
    // band buffer [128][33] f32 unioned over the ring (used after K-loop)
    __shared__ __align__(16) char smem[NBUF * LDSB];
    __shared__ int   s_cam[BN];
    __shared__ float c2buf[BM][2];
    float* bandS = (float*)smem;

    // ---- A staging (global_load_lds): 2 issues/thread/chunk
    // r_idx = t + i*256: plane=r_idx>>8, ks=(r_idx>>7)&1, row=r_idx&127
    const char* asrc[2];
    int aldso[2];
#pragma unroll
    for (int i = 0; i < 2; ++i) {
        const int rme = t + i * 256;
        const __bf16* basep = ((rme >> 8) & 1) ? Flo : Fhi;
        asrc[i] = (const char*)(basep +
                  (size_t)(p * MM + mt * BM + (rme & 127)) * DD + ((rme >> 7) & 1) * 8);
        const int rb = w * 64 + i * 256;   // wave-uniform base (lane 0 of run)
        aldso[i] = ((rb >> 8) & 1) * 4096 + ((rb >> 7) & 1) * 2048 + (rb & 127) * 16;
    }
    // ---- B staging (reg + cvt): thread owns row brow, k-octet o of each chunk
    const int brow = t & 127, bo = t >> 7;
    const float* bsrc = centers + (size_t)(p * NN + ns * BN + brow) * DD + bo * 8;
    const int bwo = bo * 2048 + brow * 16;   // byte offset within B planes

    // fragment read byte offsets (within a buffer)
    int aU[2], bU[2];
#pragma unroll
    for (int x = 0; x < 2; ++x) {
        aU[x] = lh * 2048 + (wr * 64 + x * 32 + l31) * 16;
        bU[x] = 8192 + lh * 2048 + (wc * 64 + x * 32 + l31) * 16;
    }

    f32x16 acc[2][2];
#pragma unroll
    for (int i = 0; i < 2; ++i)
#pragma unroll
        for (int j = 0; j < 2; ++j)
#pragma unroll
            for (int r = 0; r < 16; ++r) acc[i][j][r] = 0.0f;

    float c2acc = 0.0f;

    auto issueA = [&](int c) {
        char* dst = smem + (c % 3) * LDSB;
#pragma unroll
        for (int i = 0; i < 2; ++i)
            __builtin_amdgcn_global_load_lds(
                (const __attribute__((address_space(1))) void*)(asrc[i] + (size_t)c * 32),
                (__attribute__((address_space(3))) void*)(dst + aldso[i]),
                16, 0, 0);
    };
    auto issueB = [&](int c, float4& b0, float4& b1) {
        const float4* src = (const float4*)(bsrc + (size_t)c * 16);
        b0 = src[0]; b1 = src[1];
    };
    auto step = [&](int c, float4& b0, float4& b1) {
        // retire chunk c's 4 VMEM ops; keep chunk c+1's 4 in flight
        if (c + 1 < NCHUNK) asm volatile("s_waitcnt vmcnt(4)" ::: "memory");
        else                asm volatile("s_waitcnt vmcnt(0)" ::: "memory");
        {   // chunk c's B: cvt + write to LDS, accumulate c2
            bf16x8 h, l;
            cvt8(b0, b1, h, l);
            c2acc += sq8(b0, b1);
            char* dst = smem + (c % 3) * LDSB;
            *(bf16x8*)(dst + 8192  + bwo) = h;
            *(bf16x8*)(dst + 12288 + bwo) = l;
        }
        asm volatile("s_waitcnt lgkmcnt(0)" ::: "memory");   // B writes visible
        __builtin_amdgcn_s_barrier();
        __builtin_amdgcn_sched_barrier(0);                   // pin issues below barrier
        if (c + 2 < NCHUNK) { issueA(c + 2); issueB(c + 2, b0, b1); }

        const char* bb = smem + (c % 3) * LDSB;
        bf16x8 ah[2], al[2], bh[2], bl[2];
#pragma unroll
        for (int x = 0; x < 2; ++x) {
            ah[x] = *(const bf16x8*)(bb + aU[x]);
            al[x] = *(const bf16x8*)(bb + 4096 + aU[x]);
            bh[x] = *(const bf16x8*)(bb + bU[x]);
            bl[x] = *(const bf16x8*)(bb + 4096 + bU[x]);
        }
        asm volatile("s_waitcnt lgkmcnt(0)" ::: "memory");
        __builtin_amdgcn_sched_barrier(0);
        __builtin_amdgcn_s_setprio(1);
#pragma unroll
        for (int mi = 0; mi < 2; ++mi)
#pragma unroll
            for (int nj = 0; nj < 2; ++nj) {
                acc[mi][nj] = __builtin_amdgcn_mfma_f32_32x32x16_bf16(
                    ah[mi], bh[nj], acc[mi][nj], 0, 0, 0);
                acc[mi][nj] = __builtin_amdgcn_mfma_f32_32x32x16_bf16(
                    ah[mi], bl[nj], acc[mi][nj], 0, 0, 0);
                acc[mi][nj] = __builtin_amdgcn_mfma_f32_32x32x16_bf16(
                    al[mi], bh[nj], acc[mi][nj], 0, 0, 0);
            }
        __builtin_amdgcn_s_setprio(0);
    };

    // prologue: depth-2 prefetch (VMEM order: A0,B0,A1,B1)
    float4 be0, be1, bo0, bo1;
    issueA(0); issueB(0, be0, be1);
    issueA(1); issueB(1, bo0, bo1);

    for (int c = 0; c < NCHUNK; c += 2) {   // even/odd named reg sets (rule #20)
        step(c,     be0, be1);
        step(c + 1, bo0, bo1);
    }

    __syncthreads();                    // K-loop LDS reads drained everywhere

    c2buf[brow][bo] = c2acc;
    if (t < BN) s_cam[t] = cam[ns * BN + t];
    __syncthreads();                    // c2buf + s_cam visible

    float c2v[2];
#pragma unroll
    for (int nj = 0; nj < 2; ++nj) {
        const int C = wc * 64 + nj * 32 + l31;
        c2v[nj] = c2buf[C][0] + c2buf[C][1];
    }

    const int myrow = t >> 1, half = t & 1;   // 2 threads per row
    const int my_cam = camid[mt * BM + myrow];
    float ti[KI], tr[KR];
#pragma unroll
    for (int x = 0; x < KI; ++x) ti[x] = BIGV;
#pragma unroll
    for (int x = 0; x < KR; ++x) tr[x] = BIGV;
    float si = 0.0f, sr = 0.0f;

    // 4 column-bands of 32 cols; band b written by waves with wc == b>>1 (nj = b&1)
#pragma unroll
    for (int b = 0; b < 4; ++b) {
        __syncthreads();                 // previous band consumed
        if (wc == (b >> 1)) {
            const int nj = b & 1;
#pragma unroll
            for (int mi = 0; mi < 2; ++mi)
#pragma unroll
                for (int r = 0; r < 16; ++r) {
                    // C/D layout: col = lane&31, row = (r&3)+8*(r>>2)+4*(lane>>5)
                    int R = wr * 64 + mi * 32 + (r & 3) + 8 * (r >> 2) + 4 * lh;
                    bandS[R * 33 + l31] = c2v[nj] - 2.0f * acc[mi][nj][r];
                }
        }
        __syncthreads();
        const float* drow = bandS + myrow * 33 + half * 16;
        const int*   crow = s_cam + b * 32 + half * 16;
#pragma unroll
        for (int j = 0; j < 16; ++j) {
            float dd = drow[j];
            float e  = __expf(-KSCALE * dd);
            if (crow[j] == my_cam) { si += e; insert6(ti, dd); }
            else                   { sr += e; insert12(tr, dd); }
        }
    }

    // merge the 2 threads per row via lane^1 shuffle (snapshot first, then insert)
    float oti[KI], otr[KR];
#pragma unroll
    for (int x = 0; x < KI; ++x) oti[x] = __shfl_xor(ti[x], 1, 64);
#pragma unroll
    for (int x = 0; x < KR; ++x) otr[x] = __shfl_xor(tr[x], 1, 64);
    float osi = __shfl_xor(si, 1, 64), osr = __shfl_xor(sr, 1, 64);
#pragma unroll
    for (int x = 0; x < KI; ++x) insert6(ti, oti[x]);
#pragma unroll
    for (int x = 0; x < KR; ++x) insert12(tr, otr[x]);
    si += osi; sr += osr;

    if (!half) {
        float* outp = partials +
            ((size_t)(p * MM + mt * BM + myrow) * NSTRIP + ns) * PARTW;
#pragma unroll
        for (int x = 0; x < KI; ++x) outp[x] = ti[x];
#pragma unroll
        for (int x = 0; x < KR; ++x) outp[KI + x] = tr[x];
        outp[18] = si; outp[19] = sr;
    }
}

// ---------- finalize: one wave per row, lane=strip, shuffle-butterfly merge ----

__global__ __launch_bounds__(256)
void finalize_kernel(const float* __restrict__ partials, float* __restrict__ out) {
    const int t = threadIdx.x, lane = t & 63, w = t >> 6;
    const int row = blockIdx.x * 4 + w;        // 0..P*M-1
    const int strip = lane & 31;               // lanes 32-63 mirror (harmless)
    const float* q = partials + ((size_t)row * NSTRIP + strip) * PARTW;
    float ti[KI], tr[KR];
#pragma unroll
    for (int x = 0; x < KI; ++x) ti[x] = q[x];
#pragma unroll
    for (int x = 0; x < KR; ++x) tr[x] = q[KI + x];
    float si = q[18], sr = q[19];

#pragma unroll
    for (int s = 1; s < 32; s <<= 1) {
        float oti[KI], otr[KR];
#pragma unroll
        for (int x = 0; x < KI; ++x) oti[x] = __shfl_xor(ti[x], s, 64);
#pragma unroll
        for (int x = 0; x < KR; ++x) otr[x] = __shfl_xor(tr[x], s, 64);
        float osi = __shfl_xor(si, s, 64), osr = __shfl_xor(sr, s, 64);
#pragma unroll
        for (int x = 0; x < KI; ++x) insert6(ti, oti[x]);
#pragma unroll
        for (int x = 0; x < KR; ++x) insert12(tr, otr[x]);
        si += osi; sr += osr;
    }

    if (lane == 0) {
        float ei[KI], er[KR];
#pragma unroll
        for (int x = 0; x < KI; ++x) ei[x] = __expf(-KSCALE * ti[x]);
#pragma unroll
        for (int x = 0; x < KR; ++x) er[x] = __expf(-KSCALE * tr[x]);
        float x_intra = logf(ei[0] + ei[1] + ei[2] + ei[3]);
        float top6 = ei[0] + ei[1] + ei[2] + ei[3] + ei[4] + ei[5];
        float y_intra = logf(fmaxf(si - top6, 0.0f));   // exp(-15*BIG)=0 matches ref
        float x_inter = logf(er[0] + er[1] + er[2] + er[3] +
                             er[4] + er[5] + er[6] + er[7]);
        float top12 = 0.0f;
#pragma unroll
        for (int x = 0; x < KR; ++x) top12 += er[x];
        float y_inter = logf(fmaxf(sr - top12, 0.0f));
        float h = fmaxf(y_intra - x_intra + 12.0f, 0.0f) +
                  fmaxf(y_inter - x_inter + 5.0f, 0.0f);
        atomicAdd(out, h * (1.0f / (MM * PP)));
    }
}

extern "C" void kernel_launch(void* const* d_in, const int* in_sizes, int n_in,
                              void* d_out, int out_size, void* d_ws, size_t ws_size,
                              hipStream_t stream) {
    const float* feature = (const float*)d_in[0];   // [P,M,D] fp32
    const int*   camid   = (const int*)  d_in[1];   // [M]
    const float* centers = (const float*)d_in[2];   // [P,N,D] fp32
    const int*   cam     = (const int*)  d_in[3];   // [N]
    float* out = (float*)d_out;

    // ws layout (bytes): Fhi 6,291,456 | Flo 6,291,456 | partials 7,864,320
    //   total 20,447,232 (vs 121 MB before -> cheap re-poison)
    char* ws = (char*)d_ws;
    __bf16* Fhi = (__bf16*)(ws);
    __bf16* Flo = (__bf16*)(ws + 6291456);
    float*  partials = (float*)(ws + 12582912);

    decomp_feat<<<(PP * MM) / 4, 256, 0, stream>>>(feature, Fhi, Flo, out);
    dim3 grid(NSTRIP, MM / BM, PP);
    dist_topk_kernel<<<grid, 256, 0, stream>>>(Fhi, Flo, centers,
                                               camid, cam, partials);
    finalize_kernel<<<(PP * MM) / 4, 256, 0, stream>>>(partials, out);
}